// Round 1
// baseline (222.253 us; speedup 1.0000x reference)
//
#include <hip/hip_runtime.h>
#include <math.h>
#include <stdint.h>

#define B_ROWS 2048
#define D_DIM  512
#define V_COLS 32000
#define BM 256
#define BN 256
#define BK 64
#define KSTEPS (D_DIM / BK)             // 8
#define NRT    (B_ROWS / BM)            // 8 row tiles
#define NCT    (V_COLS / BN)            // 125 col tiles
#define S_SC   30.0f
#define COS_M  0.8775825618903728f      // cos(0.5)
#define SIN_M  0.479425538604203f       // sin(0.5)

typedef float f32x4 __attribute__((ext_vector_type(4)));
typedef long  i64x2 __attribute__((ext_vector_type(2)));

__device__ __forceinline__ void load16_to_lds(const void* g, void* l) {
  __builtin_amdgcn_global_load_lds(
      (__attribute__((address_space(1))) void*)(g),
      (__attribute__((address_space(3))) void*)(l),
      16, 0, 0);
}

// ---------- kernel 1: fused row L2-normalize (x,W) fp32 -> fp8 e4m3, + zero rowsum/out ----------
__global__ void fused_norm_kernel(const float* __restrict__ x,
                                  const float* __restrict__ W,
                                  uint8_t* __restrict__ nx,
                                  uint8_t* __restrict__ nw,
                                  float* __restrict__ rowsum,
                                  float* __restrict__ out) {
  if (blockIdx.x == 0 && threadIdx.x == 0) out[0] = 0.f;
  if (blockIdx.x < B_ROWS / 256) rowsum[blockIdx.x * 256 + threadIdx.x] = 0.f;
  const int lane = threadIdx.x & 63;
  const int wave = threadIdx.x >> 6;
  const int gr   = blockIdx.x * 4 + wave;
  const float* src;
  uint8_t* dst;
  if (gr < B_ROWS) {
    src = x + (size_t)gr * D_DIM;
    dst = nx + (size_t)gr * D_DIM;
  } else {
    src = W + (size_t)(gr - B_ROWS) * D_DIM;
    dst = nw + (size_t)(gr - B_ROWS) * D_DIM;
  }
  const float4* r4 = (const float4*)src;
  float4 v0 = r4[2 * lane];
  float4 v1 = r4[2 * lane + 1];
  float ss = v0.x*v0.x + v0.y*v0.y + v0.z*v0.z + v0.w*v0.w
           + v1.x*v1.x + v1.y*v1.y + v1.z*v1.z + v1.w*v1.w;
  #pragma unroll
  for (int off = 32; off >= 1; off >>= 1) ss += __shfl_xor(ss, off, 64);
  float inv = 1.0f / fmaxf(sqrtf(ss), 1e-12f);
  int p0 = __builtin_amdgcn_cvt_pk_fp8_f32(v0.x * inv, v0.y * inv, 0, false);
  p0     = __builtin_amdgcn_cvt_pk_fp8_f32(v0.z * inv, v0.w * inv, p0, true);
  int p1 = __builtin_amdgcn_cvt_pk_fp8_f32(v1.x * inv, v1.y * inv, 0, false);
  p1     = __builtin_amdgcn_cvt_pk_fp8_f32(v1.z * inv, v1.w * inv, p1, true);
  ((int2*)dst)[lane] = make_int2(p0, p1);
}

// ---------- kernel 2: fp8 GEMM (nx @ nW^T), 256x256 tile, triple-buffered counted-vmcnt ----------
// R11 restructure: the 2-barrier dbuf 128^2 loop (R4..R10) sat at MfmaUtil ~31% -- the
// __syncthreads() pair per K-step drains vmcnt(0)+lgkmcnt(0), starving the matrix pipe
// (known ~35% structure ceiling). New structure per the T-catalog:
//   T1: bijective XCD swizzle (1000 wg, 1000%8==0 -> exact 125/XCD slabs)
//   T2: proven fp8 LDS involution swizzle carried over (measured 0 conflicts)
//   T3/T4: triple-buffered K-tiles (3x32KB LDS) -> ONE raw s_barrier + counted
//          s_waitcnt vmcnt(4) per K-tile; tile t+2's loads issue into the buffer last
//          read at tile t-1 (fenced by the previous barrier) => race-free with loads
//          permanently in flight; vmcnt never drains to 0 until the tail.
//   T5: s_setprio(1) around the 64-MFMA cluster.
// 8 waves (2M x 4N), per-wave 128x64 out, acc[8][4]; 12 ds_read_b128 + 64 MFMA per
// K-tile per wave; 4 global_load_lds per thread per K-tile (half-tile = 128 rows =
// exactly 512 lanes x 16 B).
__global__ __launch_bounds__(512, 2)
void arc_gemm_kernel(const uint8_t* __restrict__ nx,
                     const uint8_t* __restrict__ nw,
                     const int* __restrict__ labels,
                     float* __restrict__ rowsum,
                     float* __restrict__ lbl_logit) {
  __shared__ uint8_t sA[3][BM * BK];   // 3 x 16 KB
  __shared__ uint8_t sB[3][BN * BK];   // 3 x 16 KB  (96 KB total, 1 block/CU)

  const int id = blockIdx.x;
  // bijective XCD swizzle: xcd = id & 7 gets wgids [125*xcd, 125*(xcd+1))
  const int wg = (id & 7) * NCT + (id >> 3);
  const int m0 = (wg & (NRT - 1)) * BM;
  const int n0 = (wg >> 3) * BN;

  const int tid  = threadIdx.x;
  const int wave = tid >> 6;          // 0..7
  const int lane = tid & 63;
  const int wm   = wave >> 2;         // 0..1 : row half of the tile
  const int wn   = wave & 3;          // 0..3 : col quarter
  const int quad = lane >> 4;
  const int l16  = lane & 15;

  // staging: thread covers row srow (+128 for second half-tile), 16B chunk jg.
  // jg involution: LDS[row][slot] holds global chunk slot ^ ((row>>1)&3).
  const int srow = tid >> 2;          // 0..127
  const int jg   = (tid & 3) ^ ((srow >> 1) & 3);
  const uint8_t* gA = nx + (size_t)(m0 + srow) * D_DIM + jg * 16;
  const uint8_t* gB = nw + (size_t)(n0 + srow) * D_DIM + jg * 16;
  const int ldsW = wave * 1024;       // wave-uniform base; HW adds lane*16

  // frag reads: row stride 64 B; reading slot quad^((row>>1)&3) returns global
  // chunk 'quad' => K-window permutation identical on A and B (order-invariant).
  const int cSlot = (quad ^ ((l16 >> 1) & 3)) << 4;
  const int aBase = (wm * 128 + l16) * BK + cSlot;   // + mi*1024
  const int bBase = (wn * 64  + l16) * BK + cSlot;   // + ni*1024

  f32x4 acc[8][4];
  #pragma unroll
  for (int i = 0; i < 8; ++i)
    #pragma unroll
    for (int j = 0; j < 4; ++j) acc[i][j] = (f32x4){0.f, 0.f, 0.f, 0.f};

#define STAGE(buf, t) do {                                        \
    const int _o = (t) * BK;                                      \
    load16_to_lds(gA + _o,               &sA[(buf)][ldsW]);       \
    load16_to_lds(gA + 128 * D_DIM + _o, &sA[(buf)][8192 + ldsW]);\
    load16_to_lds(gB + _o,               &sB[(buf)][ldsW]);       \
    load16_to_lds(gB + 128 * D_DIM + _o, &sB[(buf)][8192 + ldsW]);\
  } while (0)

  // prologue: tiles 0 and 1 in flight (8 loads/thread)
  STAGE(0, 0);
  STAGE(1, 1);

  #pragma unroll
  for (int t = 0; t < KSTEPS; ++t) {
    // boundary: tile t's 4 loads (oldest) must land; tile t+1's 4 stay in flight.
    if (t < KSTEPS - 1) asm volatile("s_waitcnt vmcnt(4)" ::: "memory");
    else                asm volatile("s_waitcnt vmcnt(0)" ::: "memory");
    __builtin_amdgcn_s_barrier();          // all waves' tile-t loads now visible
    __builtin_amdgcn_sched_barrier(0);     // nothing crosses the barrier
    if (t + 2 < KSTEPS) STAGE((t + 2) % 3, t + 2);   // into buffer read at t-1
    __builtin_amdgcn_sched_barrier(0);     // keep load issue ahead of compute

    const uint8_t* bA = sA[t % 3];
    const uint8_t* bB = sB[t % 3];
    i64x2 a2[8];
    #pragma unroll
    for (int mi = 0; mi < 8; ++mi)
      a2[mi] = *(const i64x2*)(bA + aBase + mi * 1024);
    __builtin_amdgcn_s_setprio(1);
    #pragma unroll
    for (int ni = 0; ni < 4; ++ni) {
      const i64x2 b2 = *(const i64x2*)(bB + bBase + ni * 1024);
      #pragma unroll
      for (int mi = 0; mi < 8; ++mi) {
        acc[mi][ni] = __builtin_amdgcn_mfma_f32_16x16x32_fp8_fp8(a2[mi][0], b2[0], acc[mi][ni], 0, 0, 0);
        acc[mi][ni] = __builtin_amdgcn_mfma_f32_16x16x32_fp8_fp8(a2[mi][1], b2[1], acc[mi][ni], 0, 0, 0);
      }
    }
    __builtin_amdgcn_s_setprio(0);
  }
#undef STAGE

  // Epilogue (R4-proven math). C/D layout: col = l16, row = mi*16 + quad*4 + r.
  const int rowbase = m0 + wm * 128;
  const int lblv0 = labels[rowbase + lane];
  const int lblv1 = labels[rowbase + 64 + lane];
  #pragma unroll
  for (int mi = 0; mi < 8; ++mi) {
    #pragma unroll
    for (int r = 0; r < 4; ++r) {
      const int rw   = mi * 16 + quad * 4 + r;     // 0..127 within wave's rows
      const int grow = rowbase + rw;
      const int lbl  = __shfl(mi < 4 ? lblv0 : lblv1,
                              (mi & 3) * 16 + quad * 4 + r, 64);
      float rsum = 0.f;
      #pragma unroll
      for (int ni = 0; ni < 4; ++ni) {
        float c = acc[mi][ni][r];
        const int gcol = n0 + wn * 64 + ni * 16 + l16;
        if (gcol == lbl) {
          float sy  = sqrtf(fminf(1.f, fmaxf(0.f, 1.f - c * c)));
          float phi = c * COS_M - sy * SIN_M;
          lbl_logit[grow] = S_SC * phi;            // exactly one lane grid-wide
          c = phi;
        }
        rsum += __expf(S_SC * c - 30.0f);          // fixed shift: logits in [-30,30]
      }
      #pragma unroll
      for (int off = 1; off < 16; off <<= 1)
        rsum += __shfl_xor(rsum, off, 64);
      if (l16 == 0) atomicAdd(&rowsum[grow], rsum);
    }
  }
}

// ---------- kernel 3: per-row loss + global mean ----------
__global__ void arc_finish_kernel(const float* __restrict__ rowsum,
                                  const float* __restrict__ lbl_logit,
                                  float* __restrict__ out) {
  const int row  = blockIdx.x * 256 + threadIdx.x;   // 8 blocks x 256
  const int lane = threadIdx.x & 63;
  const int wave = threadIdx.x >> 6;
  float v = (30.0f + logf(rowsum[row]) - lbl_logit[row]) * (1.0f / (float)B_ROWS);
  #pragma unroll
  for (int off = 32; off >= 1; off >>= 1) v += __shfl_xor(v, off, 64);
  __shared__ float wsum[4];
  if (lane == 0) wsum[wave] = v;
  __syncthreads();
  if (threadIdx.x == 0) atomicAdd(out, wsum[0] + wsum[1] + wsum[2] + wsum[3]);
}

// ---------- launch ----------
extern "C" void kernel_launch(void* const* d_in, const int* in_sizes, int n_in,
                              void* d_out, int out_size, void* d_ws, size_t ws_size,
                              hipStream_t stream) {
  const float* x      = (const float*)d_in[0];
  const float* W      = (const float*)d_in[1];
  const int*   labels = (const int*)d_in[2];
  float* out = (float*)d_out;

  char* ws = (char*)d_ws;
  uint8_t* nx = (uint8_t*)ws;                                       // 1 MB
  uint8_t* nw = (uint8_t*)(ws + (size_t)B_ROWS * D_DIM);            // 16.4 MB
  char* p = ws + (size_t)B_ROWS * D_DIM + (size_t)V_COLS * D_DIM;
  float* rowsum    = (float*)p;  p += (size_t)B_ROWS * 4;           // 8 KB
  float* lbl_logit = (float*)p;                                     // 8 KB

  hipLaunchKernelGGL(fused_norm_kernel, dim3((B_ROWS + V_COLS) / 4), dim3(256), 0, stream,
                     x, W, nx, nw, rowsum, out);
  hipLaunchKernelGGL(arc_gemm_kernel, dim3(NRT * NCT), dim3(512), 0, stream,
                     nx, nw, labels, rowsum, lbl_logit);
  hipLaunchKernelGGL(arc_finish_kernel, dim3(B_ROWS / 256), dim3(256), 0, stream,
                     rowsum, lbl_logit, out);
}

// Round 2
// 216.389 us; speedup vs baseline: 1.0271x; 1.0271x over previous
//
#include <hip/hip_runtime.h>
#include <math.h>
#include <stdint.h>

#define B_ROWS 2048
#define D_DIM  512
#define V_COLS 32000
#define BM 256
#define BN 256
#define BK 64
#define KSTEPS (D_DIM / BK)             // 8
#define NRT    (B_ROWS / BM)            // 8 row tiles
#define NCT    (V_COLS / BN)            // 125 col tiles
#define S_SC   30.0f
#define COS_M  0.8775825618903728f      // cos(0.5)
#define SIN_M  0.479425538604203f       // sin(0.5)

typedef float f32x4 __attribute__((ext_vector_type(4)));
typedef long  i64x2 __attribute__((ext_vector_type(2)));

__device__ __forceinline__ void load16_to_lds(const void* g, void* l) {
  __builtin_amdgcn_global_load_lds(
      (__attribute__((address_space(1))) void*)(g),
      (__attribute__((address_space(3))) void*)(l),
      16, 0, 0);
}

// ---------- kernel 1: fused row L2-normalize (x,W) fp32 -> fp8 e4m3, + zero rowsum/out ----------
__global__ void fused_norm_kernel(const float* __restrict__ x,
                                  const float* __restrict__ W,
                                  uint8_t* __restrict__ nx,
                                  uint8_t* __restrict__ nw,
                                  float* __restrict__ rowsum,
                                  float* __restrict__ out) {
  if (blockIdx.x == 0 && threadIdx.x == 0) out[0] = 0.f;
  if (blockIdx.x < B_ROWS / 256) rowsum[blockIdx.x * 256 + threadIdx.x] = 0.f;
  const int lane = threadIdx.x & 63;
  const int wave = threadIdx.x >> 6;
  const int gr   = blockIdx.x * 4 + wave;
  const float* src;
  uint8_t* dst;
  if (gr < B_ROWS) {
    src = x + (size_t)gr * D_DIM;
    dst = nx + (size_t)gr * D_DIM;
  } else {
    src = W + (size_t)(gr - B_ROWS) * D_DIM;
    dst = nw + (size_t)(gr - B_ROWS) * D_DIM;
  }
  const float4* r4 = (const float4*)src;
  float4 v0 = r4[2 * lane];
  float4 v1 = r4[2 * lane + 1];
  float ss = v0.x*v0.x + v0.y*v0.y + v0.z*v0.z + v0.w*v0.w
           + v1.x*v1.x + v1.y*v1.y + v1.z*v1.z + v1.w*v1.w;
  #pragma unroll
  for (int off = 32; off >= 1; off >>= 1) ss += __shfl_xor(ss, off, 64);
  float inv = 1.0f / fmaxf(sqrtf(ss), 1e-12f);
  int p0 = __builtin_amdgcn_cvt_pk_fp8_f32(v0.x * inv, v0.y * inv, 0, false);
  p0     = __builtin_amdgcn_cvt_pk_fp8_f32(v0.z * inv, v0.w * inv, p0, true);
  int p1 = __builtin_amdgcn_cvt_pk_fp8_f32(v1.x * inv, v1.y * inv, 0, false);
  p1     = __builtin_amdgcn_cvt_pk_fp8_f32(v1.z * inv, v1.w * inv, p1, true);
  ((int2*)dst)[lane] = make_int2(p0, p1);
}

// ---------- kernel 2: fp8 GEMM (nx @ nW^T), 256x256, m201-style 4-phase/K-tile schedule ----------
// R12: R11's coarse one-barrier-per-tile loop hit the m196 failure mode (MfmaUtil 18.5%).
// Keep R11's proven pieces (3-buffer K-pipeline, counted vmcnt(4) once/tile, bijective
// XCD swizzle, zero-conflict LDS involution, epilogue) but split each K-tile into 4
// phases of exactly 16 MFMA per the m201 template:
//   phase = { ds_read frag subtile ; 1 global_load_lds (tile t+2) ; s_barrier ;
//             lgkmcnt(0)+sched_barrier ; setprio(1) ; 16 MFMA ; setprio(0) ; s_barrier }
// ds_reads per phase: 6/4/2/0 (A read once per tile into a2[8], B once into b2[4]).
// vmcnt(4) only in the closing phase of each tile -- drains tile t+1's loads (issued a
// full tile earlier, ~free) and keeps tile t+2's 4 loads in flight across barriers.
__global__ __launch_bounds__(512, 2)
void arc_gemm_kernel(const uint8_t* __restrict__ nx,
                     const uint8_t* __restrict__ nw,
                     const int* __restrict__ labels,
                     float* __restrict__ rowsum,
                     float* __restrict__ lbl_logit) {
  __shared__ uint8_t sA[3][BM * BK];   // 3 x 16 KB
  __shared__ uint8_t sB[3][BN * BK];   // 3 x 16 KB  (96 KB total, 1 block/CU)

  const int id = blockIdx.x;
  // bijective XCD swizzle: 1000 wg, xcd = id & 7 owns wgids [125*xcd, 125*(xcd+1))
  const int wg = (id & 7) * NCT + (id >> 3);
  const int m0 = (wg & (NRT - 1)) * BM;
  const int n0 = (wg >> 3) * BN;

  const int tid  = threadIdx.x;
  const int wave = tid >> 6;          // 0..7
  const int lane = tid & 63;
  const int wm   = wave >> 2;         // 0..1 : row half
  const int wn   = wave & 3;          // 0..3 : col quarter
  const int quad = lane >> 4;
  const int l16  = lane & 15;

  // staging: thread covers row srow (+128 for the second half-tile), 16B chunk jg.
  // involution: LDS[row][slot] holds global chunk slot ^ ((row>>1)&3).
  const int srow = tid >> 2;          // 0..127
  const int jg   = (tid & 3) ^ ((srow >> 1) & 3);
  const uint8_t* gA = nx + (size_t)(m0 + srow) * D_DIM + jg * 16;
  const uint8_t* gB = nw + (size_t)(n0 + srow) * D_DIM + jg * 16;
  const int ldsW = wave * 1024;       // wave-uniform base; HW adds lane*16

  // frag reads: row stride 64 B; slot quad^((row>>1)&3) returns global chunk 'quad'
  // => identical K-window permutation on A and B (contraction order-invariant).
  const int cSlot = (quad ^ ((l16 >> 1) & 3)) << 4;
  const int aBase = (wm * 128 + l16) * BK + cSlot;   // + mi*1024
  const int bBase = (wn * 64  + l16) * BK + cSlot;   // + ni*1024

  f32x4 acc[8][4];
  #pragma unroll
  for (int i = 0; i < 8; ++i)
    #pragma unroll
    for (int j = 0; j < 4; ++j) acc[i][j] = (f32x4){0.f, 0.f, 0.f, 0.f};

#define STAGE(buf, t) do {                                        \
    const int _o = (t) * BK;                                      \
    load16_to_lds(gA + _o,               &sA[(buf)][ldsW]);       \
    load16_to_lds(gA + 128 * D_DIM + _o, &sA[(buf)][8192 + ldsW]);\
    load16_to_lds(gB + _o,               &sB[(buf)][ldsW]);       \
    load16_to_lds(gB + 128 * D_DIM + _o, &sB[(buf)][8192 + ldsW]);\
  } while (0)

#define MFMA2(mi, ni)                                                                          \
    acc[mi][ni] = __builtin_amdgcn_mfma_f32_16x16x32_fp8_fp8(a2[mi][0], b2[ni][0], acc[mi][ni], 0, 0, 0); \
    acc[mi][ni] = __builtin_amdgcn_mfma_f32_16x16x32_fp8_fp8(a2[mi][1], b2[ni][1], acc[mi][ni], 0, 0, 0)

#define PHASE_OPEN()                                      \
    __builtin_amdgcn_sched_barrier(0);                    \
    __builtin_amdgcn_s_barrier();                         \
    asm volatile("s_waitcnt lgkmcnt(0)" ::: "memory");    \
    __builtin_amdgcn_sched_barrier(0);                    \
    __builtin_amdgcn_s_setprio(1)

#define PHASE_CLOSE()                                     \
    __builtin_amdgcn_s_setprio(0);                        \
    __builtin_amdgcn_sched_barrier(0);                    \
    __builtin_amdgcn_s_barrier()

  // prologue: tiles 0 and 1 in flight (8 loads/thread)
  STAGE(0, 0);
  STAGE(1, 1);
  asm volatile("s_waitcnt vmcnt(4)" ::: "memory");   // tile 0 resident; tile 1 in flight
  __builtin_amdgcn_s_barrier();

  #pragma unroll
  for (int t = 0; t < KSTEPS; ++t) {
    const uint8_t* bA = sA[t % 3];
    const uint8_t* bB = sB[t % 3];
    const int  sb = (t + 2) % 3;           // stage buffer: last read at tile t-1
    const int  so = (t + 2) * BK;
    const bool st = (t + 2 < KSTEPS);
    i64x2 a2[8];
    i64x2 b2[4];

    // ---- phase 0: read A[0..3], B[0..1]; stage A-half0(t+2); mfma n={0,1} x m={0..3}
    #pragma unroll
    for (int mi = 0; mi < 4; ++mi) a2[mi] = *(const i64x2*)(bA + aBase + mi * 1024);
    b2[0] = *(const i64x2*)(bB + bBase);
    b2[1] = *(const i64x2*)(bB + bBase + 1024);
    if (st) load16_to_lds(gA + so, &sA[sb][ldsW]);
    PHASE_OPEN();
    MFMA2(0, 0); MFMA2(1, 0); MFMA2(2, 0); MFMA2(3, 0);
    MFMA2(0, 1); MFMA2(1, 1); MFMA2(2, 1); MFMA2(3, 1);
    PHASE_CLOSE();

    // ---- phase 1: read A[4..7]; stage A-half1(t+2); mfma n={0,1} x m={4..7}
    #pragma unroll
    for (int mi = 4; mi < 8; ++mi) a2[mi] = *(const i64x2*)(bA + aBase + mi * 1024);
    if (st) load16_to_lds(gA + 128 * D_DIM + so, &sA[sb][8192 + ldsW]);
    PHASE_OPEN();
    MFMA2(4, 0); MFMA2(5, 0); MFMA2(6, 0); MFMA2(7, 0);
    MFMA2(4, 1); MFMA2(5, 1); MFMA2(6, 1); MFMA2(7, 1);
    PHASE_CLOSE();

    // ---- phase 2: read B[2..3]; stage B-half0(t+2); mfma n={2,3} x m={0..3}
    b2[2] = *(const i64x2*)(bB + bBase + 2048);
    b2[3] = *(const i64x2*)(bB + bBase + 3072);
    if (st) load16_to_lds(gB + so, &sB[sb][ldsW]);
    PHASE_OPEN();
    MFMA2(0, 2); MFMA2(1, 2); MFMA2(2, 2); MFMA2(3, 2);
    MFMA2(0, 3); MFMA2(1, 3); MFMA2(2, 3); MFMA2(3, 3);
    PHASE_CLOSE();

    // ---- phase 3: stage B-half1(t+2); mfma n={2,3} x m={4..7}; counted vmcnt; barrier
    if (st) load16_to_lds(gB + 128 * D_DIM + so, &sB[sb][8192 + ldsW]);
    __builtin_amdgcn_sched_barrier(0);
    __builtin_amdgcn_s_barrier();
    asm volatile("s_waitcnt lgkmcnt(0)" ::: "memory");
    __builtin_amdgcn_sched_barrier(0);
    __builtin_amdgcn_s_setprio(1);
    MFMA2(4, 2); MFMA2(5, 2); MFMA2(6, 2); MFMA2(7, 2);
    MFMA2(4, 3); MFMA2(5, 3); MFMA2(6, 3); MFMA2(7, 3);
    __builtin_amdgcn_s_setprio(0);
    // tile boundary: drain tile t+1's 4 loads (issued during tile t-1, ~free);
    // keep tile t+2's 4 in flight. Never 0 until the pipeline tail.
    if (t < KSTEPS - 2)       asm volatile("s_waitcnt vmcnt(4)" ::: "memory");
    else if (t == KSTEPS - 2) asm volatile("s_waitcnt vmcnt(0)" ::: "memory");
    __builtin_amdgcn_sched_barrier(0);
    __builtin_amdgcn_s_barrier();
  }
#undef STAGE
#undef MFMA2
#undef PHASE_OPEN
#undef PHASE_CLOSE

  // Epilogue (R4-proven math). C/D layout: col = l16, row = mi*16 + quad*4 + r.
  const int rowbase = m0 + wm * 128;
  const int lblv0 = labels[rowbase + lane];
  const int lblv1 = labels[rowbase + 64 + lane];
  #pragma unroll
  for (int mi = 0; mi < 8; ++mi) {
    #pragma unroll
    for (int r = 0; r < 4; ++r) {
      const int rw   = mi * 16 + quad * 4 + r;     // 0..127 within wave's rows
      const int grow = rowbase + rw;
      const int lbl  = __shfl(mi < 4 ? lblv0 : lblv1,
                              (mi & 3) * 16 + quad * 4 + r, 64);
      float rsum = 0.f;
      #pragma unroll
      for (int ni = 0; ni < 4; ++ni) {
        float c = acc[mi][ni][r];
        const int gcol = n0 + wn * 64 + ni * 16 + l16;
        if (gcol == lbl) {
          float sy  = sqrtf(fminf(1.f, fmaxf(0.f, 1.f - c * c)));
          float phi = c * COS_M - sy * SIN_M;
          lbl_logit[grow] = S_SC * phi;            // exactly one lane grid-wide
          c = phi;
        }
        rsum += __expf(S_SC * c - 30.0f);          // fixed shift: logits in [-30,30]
      }
      #pragma unroll
      for (int off = 1; off < 16; off <<= 1)
        rsum += __shfl_xor(rsum, off, 64);
      if (l16 == 0) atomicAdd(&rowsum[grow], rsum);
    }
  }
}

// ---------- kernel 3: per-row loss + global mean ----------
__global__ void arc_finish_kernel(const float* __restrict__ rowsum,
                                  const float* __restrict__ lbl_logit,
                                  float* __restrict__ out) {
  const int row  = blockIdx.x * 256 + threadIdx.x;   // 8 blocks x 256
  const int lane = threadIdx.x & 63;
  const int wave = threadIdx.x >> 6;
  float v = (30.0f + logf(rowsum[row]) - lbl_logit[row]) * (1.0f / (float)B_ROWS);
  #pragma unroll
  for (int off = 32; off >= 1; off >>= 1) v += __shfl_xor(v, off, 64);
  __shared__ float wsum[4];
  if (lane == 0) wsum[wave] = v;
  __syncthreads();
  if (threadIdx.x == 0) atomicAdd(out, wsum[0] + wsum[1] + wsum[2] + wsum[3]);
}

// ---------- launch ----------
extern "C" void kernel_launch(void* const* d_in, const int* in_sizes, int n_in,
                              void* d_out, int out_size, void* d_ws, size_t ws_size,
                              hipStream_t stream) {
  const float* x      = (const float*)d_in[0];
  const float* W      = (const float*)d_in[1];
  const int*   labels = (const int*)d_in[2];
  float* out = (float*)d_out;

  char* ws = (char*)d_ws;
  uint8_t* nx = (uint8_t*)ws;                                       // 1 MB
  uint8_t* nw = (uint8_t*)(ws + (size_t)B_ROWS * D_DIM);            // 16.4 MB
  char* p = ws + (size_t)B_ROWS * D_DIM + (size_t)V_COLS * D_DIM;
  float* rowsum    = (float*)p;  p += (size_t)B_ROWS * 4;           // 8 KB
  float* lbl_logit = (float*)p;                                     // 8 KB

  hipLaunchKernelGGL(fused_norm_kernel, dim3((B_ROWS + V_COLS) / 4), dim3(256), 0, stream,
                     x, W, nx, nw, rowsum, out);
  hipLaunchKernelGGL(arc_gemm_kernel, dim3(NRT * NCT), dim3(512), 0, stream,
                     nx, nw, labels, rowsum, lbl_logit);
  hipLaunchKernelGGL(arc_finish_kernel, dim3(B_ROWS / 256), dim3(256), 0, stream,
                     rowsum, lbl_logit, out);
}